// Round 6
// baseline (114.303 us; speedup 1.0000x reference)
//
#include <hip/hip_runtime.h>

#define HH 256
#define WW 512
#define CC 64
#define CO 16
#define DD 48   // MAX_DISPARITY; output has D+1 = 49 disparity planes

typedef float f32x4 __attribute__((ext_vector_type(4)));

// Kernel 1: per-pixel 16x64 matvec for both L and R projections.
__global__ __launch_bounds__(256) void lr_project(
    const float* __restrict__ left, const float* __restrict__ right,
    const float* __restrict__ Wop,
    float* __restrict__ Lout, float* __restrict__ Rout)
{
    const int tid = blockIdx.x * blockDim.x + threadIdx.x;  // 0 .. H*W-1
    const int x = tid & (WW - 1);
    const int y = tid >> 9;   // /512

    float accL[CO], accR[CO];
#pragma unroll
    for (int o = 0; o < CO; ++o) { accL[o] = 0.0f; accR[o] = 0.0f; }

#pragma unroll 4
    for (int c = 0; c < CC; ++c) {
        const float l = left [(c * HH + y) * WW + x];
        const float r = right[(c * HH + y) * WW + x];
#pragma unroll
        for (int o = 0; o < CO; ++o) {
            accL[o] += Wop[o * (2 * CC) + c]      * l;
            accR[o] += Wop[o * (2 * CC) + CC + c] * r;
        }
    }

#pragma unroll
    for (int o = 0; o < CO; ++o) {
        Lout[(o * HH + y) * WW + x] = accL[o];
        Rout[(o * HH + y) * WW + x] = accR[o];
    }
}

// Kernel 2: out[o,d,y,x] = L[o,y,x] + (x>=d ? R[o,y,x-d] : 0) + b[o]
// Round-4 structure (register window, no in-loop loads), but with PLAIN
// stores — A/B test: is the nontemporal hint capping write BW at ~4.7 TB/s?
__global__ __launch_bounds__(256) void assemble(
    const float* __restrict__ L, const float* __restrict__ R,
    const float* __restrict__ bop, float* __restrict__ out)
{
    const int tid = blockIdx.x * blockDim.x + threadIdx.x;  // 0 .. CO*H*W/4-1
    const int x4 = tid & 127;        // W/4 = 128
    const int t  = tid >> 7;
    const int y  = t & 255;          // H = 256
    const int o  = t >> 8;

    const int x   = x4 * 4;
    const int row = (o * HH + y) * WW;

    const float  b  = bop[o];
    const f32x4  lv = *reinterpret_cast<const f32x4*>(&L[row + x]);
    const float lb0 = lv.x + b, lb1 = lv.y + b, lb2 = lv.z + b, lb3 = lv.w + b;

    const float* Rrow = &R[row];

    // w[k] = R[row + x - 48 + k] for k=0..51 (zero where x-48+k < 0).
    float w[52];
#pragma unroll
    for (int jr = 0; jr < 13; ++jr) {
        const int j = 12 - jr;
        const int base = x - 48 + 4 * j;
        // speculative aligned load; base >= -48 stays inside d_ws (L region)
        f32x4 v = *reinterpret_cast<const f32x4*>(&Rrow[base]);
        const bool ok = (base >= 0);
        w[4 * j + 0] = ok ? v.x : 0.0f;
        w[4 * j + 1] = ok ? v.y : 0.0f;
        w[4 * j + 2] = ok ? v.z : 0.0f;
        w[4 * j + 3] = ok ? v.w : 0.0f;
    }

    float* outp = &out[((size_t)(o * (DD + 1)) * HH + y) * WW + x];

#pragma unroll
    for (int d = 0; d <= DD; ++d) {
        f32x4 ov;
        ov.x = lb0 + w[48 - d];
        ov.y = lb1 + w[49 - d];
        ov.z = lb2 + w[50 - d];
        ov.w = lb3 + w[51 - d];
        *reinterpret_cast<f32x4*>(outp) = ov;   // plain store (through L2)
        outp += HH * WW;             // next disparity plane
    }
}

extern "C" void kernel_launch(void* const* d_in, const int* in_sizes, int n_in,
                              void* d_out, int out_size, void* d_ws, size_t ws_size,
                              hipStream_t stream) {
    const float* left  = (const float*)d_in[0];
    const float* right = (const float*)d_in[1];
    const float* Wop   = (const float*)d_in[2];
    const float* bop   = (const float*)d_in[3];
    float* out = (float*)d_out;

    float* Lws = (float*)d_ws;                      // CO*H*W floats = 8 MB
    float* Rws = Lws + (size_t)CO * HH * WW;        // next 8 MB

    lr_project<<<(HH * WW) / 256, 256, 0, stream>>>(left, right, Wop, Lws, Rws);
    assemble<<<(CO * HH * (WW / 4)) / 256, 256, 0, stream>>>(Lws, Rws, bop, out);
}

// Round 7
// 108.624 us; speedup vs baseline: 1.0523x; 1.0523x over previous
//
#include <hip/hip_runtime.h>

#define HH 256
#define WW 512
#define CC 64
#define CO 16
#define DD 48            // MAX_DISPARITY
#define ND (DD + 1)      // 49 disparity planes

typedef float f32x4 __attribute__((ext_vector_type(4)));

// One fused kernel. Block = one image row y (256 blocks, 1 per CU).
// Phase 1: read left/right[c,y,:] once, project to L(+b), R; stage in LDS.
// Phase 2: pure NT store stream over the 784 (o,d) output planes.
__global__ __launch_bounds__(256, 1) void fused_matching(
    const float* __restrict__ left, const float* __restrict__ right,
    const float* __restrict__ Wop, const float* __restrict__ bop,
    float* __restrict__ out)
{
    __shared__ float Ls[CO][WW];        // L + b          (32 KB)
    __shared__ float Rs[CO][DD + WW];   // 48-zero apron + R (35.84 KB)

    const int y = blockIdx.x;
    const int t = threadIdx.x;

    // zero the left apron of Rs (16*48 = 768 slots)
    for (int i = t; i < CO * DD; i += 256)
        Rs[i / DD][i % DD] = 0.0f;

    // ---- Phase 1: projection, 2 pixels per thread ----
    {
        float aL0[CO], aL1[CO], aR0[CO], aR1[CO];
#pragma unroll
        for (int o = 0; o < CO; ++o) { aL0[o] = aL1[o] = aR0[o] = aR1[o] = 0.0f; }

        const int x0 = t, x1 = t + 256;
#pragma unroll 4
        for (int c = 0; c < CC; ++c) {
            const float l0 = left [(c * HH + y) * WW + x0];
            const float l1 = left [(c * HH + y) * WW + x1];
            const float r0 = right[(c * HH + y) * WW + x0];
            const float r1 = right[(c * HH + y) * WW + x1];
#pragma unroll
            for (int o = 0; o < CO; ++o) {
                const float wl = Wop[o * 2 * CC + c];        // wave-uniform -> SGPR
                const float wr = Wop[o * 2 * CC + CC + c];
                aL0[o] += wl * l0;  aL1[o] += wl * l1;
                aR0[o] += wr * r0;  aR1[o] += wr * r1;
            }
        }
#pragma unroll
        for (int o = 0; o < CO; ++o) {
            const float b = bop[o];
            Ls[o][x0] = aL0[o] + b;
            Ls[o][x1] = aL1[o] + b;
            Rs[o][DD + x0] = aR0[o];
            Rs[o][DD + x1] = aR1[o];
        }
    }
    __syncthreads();

    // ---- Phase 2: pure store stream ----
    // thread -> x4 = 4*(t&127); pair = t>>7 (wave-uniform).
    // od = o*ND + d walks 0..783 in steps of 2 per half-block; output
    // address advances monotonically by 2 planes per iteration.
    const int x4   = (t & 127) << 2;
    const int pair = t >> 7;

    int o = 0, d = pair;
    float* outp = &out[(size_t)pair * (HH * WW) + (size_t)y * WW + x4];

#pragma unroll 2
    for (int seg = 0; seg < (CO * ND) / 2; ++seg) {   // 392 iterations
        const f32x4 lv = *reinterpret_cast<const f32x4*>(&Ls[o][x4]);
        f32x4 rv;   // 4B-aligned LDS read at offset -d (apron makes it valid)
        __builtin_memcpy(&rv, &Rs[o][DD + x4 - d], sizeof(rv));

        const f32x4 ov = lv + rv;
        __builtin_nontemporal_store(ov, reinterpret_cast<f32x4*>(outp));

        outp += 2 * (HH * WW);
        d += 2;
        if (d >= ND) { d -= ND; ++o; }
    }
}

extern "C" void kernel_launch(void* const* d_in, const int* in_sizes, int n_in,
                              void* d_out, int out_size, void* d_ws, size_t ws_size,
                              hipStream_t stream) {
    const float* left  = (const float*)d_in[0];
    const float* right = (const float*)d_in[1];
    const float* Wop   = (const float*)d_in[2];
    const float* bop   = (const float*)d_in[3];
    float* out = (float*)d_out;

    fused_matching<<<HH, 256, 0, stream>>>(left, right, Wop, bop, out);
}